// Round 2
// baseline (1978.053 us; speedup 1.0000x reference)
//
#include <hip/hip_runtime.h>

#define N_NODES  50000
#define NPAD     50048
#define N_EDGES  640000
#define IN_CH    64
#define EDGE_DIM 16
#define HID      128
#define HID2     256
#define NLAYER   5
#define NGRAPH   128

typedef unsigned short ushort_t;
typedef __attribute__((ext_vector_type(8))) short short8;
typedef __attribute__((ext_vector_type(4))) float f32x4;

__device__ __forceinline__ float b2f(ushort_t u) {
    union { unsigned v; float f; } x; x.v = ((unsigned)u) << 16; return x.f;
}
__device__ __forceinline__ ushort_t f2b(float f) {
    union { float f; unsigned u; } x; x.f = f;
    unsigned u = x.u;
    unsigned r = (u + 0x7FFFu + ((u >> 16) & 1u)) >> 16;
    return (ushort_t)r;
}

// ---------------- prep: transpose + f32->bf16 convert ----------------
__global__ void k_transpose_cvt(const float* __restrict__ src, ushort_t* __restrict__ dst,
                                int B, int K, int Nn) {
    long total = (long)B * K * Nn;
    for (long i = (long)blockIdx.x * blockDim.x + threadIdx.x; i < total;
         i += (long)gridDim.x * blockDim.x) {
        int b = (int)(i / ((long)K * Nn));
        int rem = (int)(i - (long)b * K * Nn);
        int k = rem / Nn;
        int n = rem - k * Nn;
        dst[(long)b * K * Nn + (long)n * K + k] = f2b(src[i]);
    }
}

// W_l[k][j] = sum_i edge_w[k][i]*lin_w[l][i][j];  c_l[j] = sum_i edge_b[i]*lin_w[l][i][j] + lin_b[l][j]
__global__ __launch_bounds__(128) void k_combine(const float* __restrict__ ew,
                                                 const float* __restrict__ eb,
                                                 const float* __restrict__ lw,
                                                 const float* __restrict__ lb,
                                                 float* __restrict__ Wc, float* __restrict__ cc) {
    int l = blockIdx.x, j = threadIdx.x;
    float accW[EDGE_DIM];
#pragma unroll
    for (int k = 0; k < EDGE_DIM; ++k) accW[k] = 0.f;
    float accc = 0.f;
    for (int i = 0; i < HID; ++i) {
        float lwv = lw[((long)l * HID + i) * HID + j];
        accc = fmaf(eb[i], lwv, accc);
#pragma unroll
        for (int k = 0; k < EDGE_DIM; ++k)
            accW[k] = fmaf(ew[k * HID + i], lwv, accW[k]);
    }
#pragma unroll
    for (int k = 0; k < EDGE_DIM; ++k) Wc[(l * EDGE_DIM + k) * HID + j] = accW[k];
    cc[l * HID + j] = accc + lb[l * HID + j];
}

// ---------------- CSR build ----------------
__global__ __launch_bounds__(256) void k_hist(const int* __restrict__ ei, int* __restrict__ deg) {
    int e = blockIdx.x * 256 + threadIdx.x;
    if (e < N_EDGES) atomicAdd(&deg[ei[N_EDGES + e]], 1);
}

__global__ __launch_bounds__(1024) void k_scan1(const int* __restrict__ deg,
                                                int* __restrict__ offs, int* __restrict__ bsum) {
    __shared__ int s[1024];
    int i = blockIdx.x * 1024 + threadIdx.x;
    int v = (i < N_NODES) ? deg[i] : 0;
    s[threadIdx.x] = v;
    __syncthreads();
    for (int off = 1; off < 1024; off <<= 1) {
        int t = (threadIdx.x >= off) ? s[threadIdx.x - off] : 0;
        __syncthreads();
        s[threadIdx.x] += t;
        __syncthreads();
    }
    if (i < N_NODES) offs[i] = s[threadIdx.x] - v;  // exclusive
    if (threadIdx.x == 1023) bsum[blockIdx.x] = s[1023];
}

__global__ void k_scan2(int* __restrict__ bsum, int nb) {
    if (threadIdx.x == 0 && blockIdx.x == 0) {
        int acc = 0;
        for (int i = 0; i < nb; ++i) { int v = bsum[i]; bsum[i] = acc; acc += v; }
    }
}

__global__ __launch_bounds__(1024) void k_scan3(int* __restrict__ offs, const int* __restrict__ bsum) {
    int i = blockIdx.x * 1024 + threadIdx.x;
    if (i < N_NODES) offs[i] += bsum[blockIdx.x];
}

__global__ __launch_bounds__(256) void k_scatter(const int* __restrict__ ei,
                                                 const float* __restrict__ ea,
                                                 const int* __restrict__ offs,
                                                 int* __restrict__ cursor,
                                                 int* __restrict__ src_s,
                                                 float* __restrict__ ea_s) {
    int e = blockIdx.x * 256 + threadIdx.x;
    if (e >= N_EDGES) return;
    int d = ei[N_EDGES + e];
    int pos = offs[d] + atomicAdd(&cursor[d], 1);
    src_s[pos] = ei[e];
    const f32x4* srcp = (const f32x4*)(ea + (long)e * EDGE_DIM);
    f32x4* dst = (f32x4*)(ea_s + (long)pos * EDGE_DIM);
    dst[0] = srcp[0];
    dst[1] = srcp[1];
    dst[2] = srcp[2];
    dst[3] = srcp[3];
}

// ---------------- node encoder: h = relu(x @ node_w + node_b), f32 out ----------------
__global__ __launch_bounds__(256) void k_node_enc(const float* __restrict__ x,
                                                  const ushort_t* __restrict__ w0T,
                                                  const float* __restrict__ nb,
                                                  float* __restrict__ h) {
    __shared__ __align__(16) short lB[HID * IN_CH];  // [n=128][k=64], xor-swizzled granules
    for (int c = threadIdx.x; c < HID * IN_CH / 8; c += 256) {
        int row = c >> 3, k0 = (c & 7) * 8;
        short8 v = *(const short8*)(w0T + row * IN_CH + k0);
        int g = (k0 >> 3) ^ (row & 7);
        *(short8*)&lB[row * IN_CH + g * 8] = v;
    }
    __syncthreads();
    int wv = threadIdx.x >> 6, l6 = threadIdx.x & 63;
    int lr = l6 & 15, lg = l6 >> 4;
    int grow = blockIdx.x * 64 + wv * 16 + lr;
    f32x4 acc[8];
#pragma unroll
    for (int nt = 0; nt < 8; ++nt) acc[nt] = (f32x4){0.f, 0.f, 0.f, 0.f};
#pragma unroll
    for (int kt = 0; kt < 2; ++kt) {
        int kk = kt * 32 + lg * 8;
        short8 a = {0, 0, 0, 0, 0, 0, 0, 0};
        if (grow < N_NODES) {
            const float* xr = x + (long)grow * IN_CH + kk;
            f32x4 v0 = *(const f32x4*)xr;
            f32x4 v1 = *(const f32x4*)(xr + 4);
#pragma unroll
            for (int j = 0; j < 4; ++j) { a[j] = (short)f2b(v0[j]); a[4 + j] = (short)f2b(v1[j]); }
        }
#pragma unroll
        for (int nt = 0; nt < 8; ++nt) {
            int brow = nt * 16 + lr;
            short8 b = *(const short8*)&lB[brow * IN_CH + (((kk >> 3) ^ (brow & 7)) << 3)];
            acc[nt] = __builtin_amdgcn_mfma_f32_16x16x32_bf16(a, b, acc[nt], 0, 0, 0);
        }
    }
    int orow0 = blockIdx.x * 64 + wv * 16 + lg * 4;
#pragma unroll
    for (int nt = 0; nt < 8; ++nt) {
        int col = nt * 16 + lr;
        float bias = nb[col];
#pragma unroll
        for (int r = 0; r < 4; ++r) {
            int row = orow0 + r;
            if (row < N_NODES) h[(long)row * HID + col] = fmaxf(acc[nt][r] + bias, 0.f);
        }
    }
}

// ---------------- per-layer edge pass: z = (1+eps)*h + sum_{e->n} relu(h[src] + ea.W + c) ----------------
__global__ __launch_bounds__(256) void k_edge(const float* __restrict__ Wc,
                                              const float* __restrict__ cc,
                                              const float* __restrict__ ea_s,
                                              const int* __restrict__ src_s,
                                              const int* __restrict__ offs,
                                              const int* __restrict__ deg,
                                              const float* __restrict__ h,
                                              const float* __restrict__ epsv,
                                              ushort_t* __restrict__ z, int l) {
    int ch = threadIdx.x & (HID - 1);
    int node = blockIdx.x * 2 + (threadIdx.x >> 7);
    float w[EDGE_DIM];
#pragma unroll
    for (int k = 0; k < EDGE_DIM; ++k) w[k] = Wc[(l * EDGE_DIM + k) * HID + ch];
    float cadd = cc[l * HID + ch];
    int s0 = offs[node];
    int dg = deg[node];
    float acc = 0.f;
    for (int i = 0; i < dg; ++i) {
        int e = s0 + i;
        int s = src_s[e];
        const f32x4* ep = (const f32x4*)(ea_s + (long)e * EDGE_DIM);
        f32x4 e0 = ep[0], e1 = ep[1], e2 = ep[2], e3 = ep[3];
        float hv = h[(long)s * HID + ch];
        float q = cadd;
#pragma unroll
        for (int k = 0; k < 4; ++k) q = fmaf(e0[k], w[k], q);
#pragma unroll
        for (int k = 0; k < 4; ++k) q = fmaf(e1[k], w[4 + k], q);
#pragma unroll
        for (int k = 0; k < 4; ++k) q = fmaf(e2[k], w[8 + k], q);
#pragma unroll
        for (int k = 0; k < 4; ++k) q = fmaf(e3[k], w[12 + k], q);
        acc += fmaxf(hv + q, 0.f);
    }
    float ep1 = 1.f + epsv[l];
    float zz = fmaf(ep1, h[(long)node * HID + ch], acc);
    z[(long)node * HID + ch] = f2b(zz);
}

// ---------------- mlp1: I = relu(z @ mlp1_w + b1), bf16 out ----------------
__global__ __launch_bounds__(256) void k_mlp1(const ushort_t* __restrict__ z,
                                              const ushort_t* __restrict__ w1T,
                                              const float* __restrict__ b1,
                                              ushort_t* __restrict__ ibuf, int l) {
    __shared__ __align__(16) short lB[HID2 * HID];  // [n=256][k=128]
    const ushort_t* wsrc = w1T + (long)l * HID2 * HID;
    for (int c = threadIdx.x; c < HID2 * HID / 8; c += 256) {
        int row = c >> 4, k0 = (c & 15) * 8;
        short8 v = *(const short8*)(wsrc + row * HID + k0);
        int g = (k0 >> 3) ^ (row & 7);
        *(short8*)&lB[row * HID + g * 8] = v;
    }
    __syncthreads();
    int wv = threadIdx.x >> 6, l6 = threadIdx.x & 63;
    int lr = l6 & 15, lg = l6 >> 4;
    int grow = blockIdx.x * 64 + wv * 16 + lr;
    f32x4 acc[16];
#pragma unroll
    for (int nt = 0; nt < 16; ++nt) acc[nt] = (f32x4){0.f, 0.f, 0.f, 0.f};
    const ushort_t* zrow = z + (long)grow * HID;
#pragma unroll
    for (int kt = 0; kt < 4; ++kt) {
        int kk = kt * 32 + lg * 8;
        short8 a = *(const short8*)(zrow + kk);
#pragma unroll
        for (int nt = 0; nt < 16; ++nt) {
            int brow = nt * 16 + lr;
            short8 b = *(const short8*)&lB[brow * HID + (((kk >> 3) ^ (brow & 7)) << 3)];
            acc[nt] = __builtin_amdgcn_mfma_f32_16x16x32_bf16(a, b, acc[nt], 0, 0, 0);
        }
    }
    int orow0 = blockIdx.x * 64 + wv * 16 + lg * 4;
#pragma unroll
    for (int nt = 0; nt < 16; ++nt) {
        int col = nt * 16 + lr;
        float bias = b1[l * HID2 + col];
#pragma unroll
        for (int r = 0; r < 4; ++r) {
            int row = orow0 + r;
            ibuf[(long)row * HID2 + col] = f2b(fmaxf(acc[nt][r] + bias, 0.f));
        }
    }
}

// ---------------- mlp2: z2 = I @ mlp2_w + b2 (f32 out) + BN partial sums ----------------
__global__ __launch_bounds__(256) void k_mlp2(const ushort_t* __restrict__ ibuf,
                                              const ushort_t* __restrict__ w2T,
                                              const float* __restrict__ b2,
                                              float* __restrict__ z2,
                                              float* __restrict__ bnsum,
                                              float* __restrict__ bnssq, int l) {
    __shared__ __align__(16) short lB[HID * HID2];  // [n=128][k=256]
    const ushort_t* wsrc = w2T + (long)l * HID * HID2;
    for (int c = threadIdx.x; c < HID * HID2 / 8; c += 256) {
        int row = c >> 5, k0 = (c & 31) * 8;
        short8 v = *(const short8*)(wsrc + row * HID2 + k0);
        int g = (k0 >> 3) ^ (row & 7);
        *(short8*)&lB[row * HID2 + g * 8] = v;
    }
    __syncthreads();
    int wv = threadIdx.x >> 6, l6 = threadIdx.x & 63;
    int lr = l6 & 15, lg = l6 >> 4;
    int grow = blockIdx.x * 64 + wv * 16 + lr;
    f32x4 acc[8];
#pragma unroll
    for (int nt = 0; nt < 8; ++nt) acc[nt] = (f32x4){0.f, 0.f, 0.f, 0.f};
    const ushort_t* irow = ibuf + (long)grow * HID2;
#pragma unroll
    for (int kt = 0; kt < 8; ++kt) {
        int kk = kt * 32 + lg * 8;
        short8 a = *(const short8*)(irow + kk);
#pragma unroll
        for (int nt = 0; nt < 8; ++nt) {
            int brow = nt * 16 + lr;
            short8 b = *(const short8*)&lB[brow * HID2 + (((kk >> 3) ^ (brow & 7)) << 3)];
            acc[nt] = __builtin_amdgcn_mfma_f32_16x16x32_bf16(a, b, acc[nt], 0, 0, 0);
        }
    }
    int orow0 = blockIdx.x * 64 + wv * 16 + lg * 4;
#pragma unroll
    for (int nt = 0; nt < 8; ++nt) {
        int col = nt * 16 + lr;
        float bias = b2[l * HID + col];
        float sv = 0.f, qv = 0.f;
#pragma unroll
        for (int r = 0; r < 4; ++r) {
            int row = orow0 + r;
            float v = acc[nt][r] + bias;
            if (row < N_NODES) {
                z2[(long)row * HID + col] = v;
                sv += v;
                qv += v * v;
            }
        }
        sv += __shfl_xor(sv, 16);
        sv += __shfl_xor(sv, 32);
        qv += __shfl_xor(qv, 16);
        qv += __shfl_xor(qv, 32);
        if (lg == 0) { atomicAdd(&bnsum[col], sv); atomicAdd(&bnssq[col], qv); }
    }
}

// ---------------- BN finalize ----------------
__global__ __launch_bounds__(128) void k_bnfin(const float* __restrict__ bnsum,
                                               const float* __restrict__ bnssq,
                                               const float* __restrict__ bng,
                                               const float* __restrict__ bnb,
                                               float* __restrict__ bnA, float* __restrict__ bnB,
                                               int l) {
    int c = threadIdx.x;
    float inv = 1.f / (float)N_NODES;
    float mu = bnsum[c] * inv;
    float var = bnssq[c] * inv - mu * mu;
    float rs = rsqrtf(var + 1e-5f);
    float a = rs * bng[l * HID + c];
    bnA[c] = a;
    bnB[c] = bnb[l * HID + c] - mu * a;
}

// ---------------- BN apply + residual + relu: h = relu(z2*A + B + h) ----------------
__global__ __launch_bounds__(1024) void k_resid(const float* __restrict__ z2,
                                                const float* __restrict__ bnA,
                                                const float* __restrict__ bnB,
                                                float* __restrict__ h) {
    long i = (long)blockIdx.x * 1024 + threadIdx.x;  // grid sized exactly N_NODES*HID
    int c = (int)(i & (HID - 1));
    float v = fmaf(z2[i], bnA[c], bnB[c]) + h[i];
    h[i] = fmaxf(v, 0.f);
}

// ---------------- pooling ----------------
__global__ void k_gstart(const int* __restrict__ batch, int* __restrict__ gstart) {
    int g = threadIdx.x;
    if (g > NGRAPH) return;
    int lo = 0, hi = N_NODES;
    while (lo < hi) { int mid = (lo + hi) >> 1; if (batch[mid] < g) lo = mid + 1; else hi = mid; }
    gstart[g] = lo;
}

__global__ __launch_bounds__(128) void k_pool(const float* __restrict__ h,
                                              const int* __restrict__ gstart,
                                              float* __restrict__ pooled,
                                              float* __restrict__ outp) {
    int g = blockIdx.x, c = threadIdx.x;
    int st = gstart[g], en = gstart[g + 1];
    float s = 0.f;
    for (int i = st; i < en; ++i) s += h[(long)i * HID + c];
    float p = s / fmaxf((float)(en - st), 1.f);
    pooled[g * HID + c] = p;
    outp[g * HID + c] = p;
}

// ---------------- output MLP ----------------
__global__ __launch_bounds__(128) void k_outmlp(const float* __restrict__ pooled,
                                                const float* __restrict__ w1,
                                                const float* __restrict__ b1,
                                                const float* __restrict__ w2,
                                                const float* __restrict__ b2,
                                                float* __restrict__ outl) {
    __shared__ float pr[HID];
    __shared__ float hid[64];
    int g = blockIdx.x, t = threadIdx.x;
    pr[t] = pooled[g * HID + t];
    __syncthreads();
    if (t < 64) {
        float a = b1[t];
        for (int k = 0; k < HID; ++k) a = fmaf(pr[k], w1[k * 64 + t], a);
        hid[t] = fmaxf(a, 0.f);
    }
    __syncthreads();
    float a = b2[t];
#pragma unroll
    for (int j = 0; j < 64; ++j) a = fmaf(hid[j], w2[j * HID + t], a);
    outl[g * HID + t] = a;
}

// =====================================================================================
extern "C" void kernel_launch(void* const* d_in, const int* in_sizes, int n_in,
                              void* d_out, int out_size, void* d_ws, size_t ws_size,
                              hipStream_t stream) {
    (void)in_sizes; (void)n_in; (void)out_size; (void)ws_size;
    const float* x      = (const float*)d_in[0];
    const int*   ei     = (const int*)d_in[1];
    const float* ea     = (const float*)d_in[2];
    const int*   batch  = (const int*)d_in[3];
    const float* node_w = (const float*)d_in[4];
    const float* node_b = (const float*)d_in[5];
    const float* edge_w = (const float*)d_in[6];
    const float* edge_b = (const float*)d_in[7];
    const float* epsv   = (const float*)d_in[8];
    const float* lin_w  = (const float*)d_in[9];
    const float* lin_b  = (const float*)d_in[10];
    const float* m1w    = (const float*)d_in[11];
    const float* m1b    = (const float*)d_in[12];
    const float* m2w    = (const float*)d_in[13];
    const float* m2b    = (const float*)d_in[14];
    const float* bng    = (const float*)d_in[15];
    const float* bnb    = (const float*)d_in[16];
    const float* ow1    = (const float*)d_in[17];
    const float* ob1    = (const float*)d_in[18];
    const float* ow2    = (const float*)d_in[19];
    const float* ob2    = (const float*)d_in[20];

    char* ws = (char*)d_ws;
    size_t off = 0;
    auto alloc = [&](size_t bytes) -> char* {
        char* p = ws + off;
        off = (off + bytes + 255) & ~(size_t)255;
        return p;
    };
    float*    h      = (float*)alloc((size_t)NPAD * HID * 4);
    ushort_t* z      = (ushort_t*)alloc((size_t)NPAD * HID * 2);
    ushort_t* ibuf   = (ushort_t*)alloc((size_t)NPAD * HID2 * 2);
    float*    z2     = (float*)alloc((size_t)NPAD * HID * 4);
    float*    ea_s   = (float*)alloc((size_t)N_EDGES * EDGE_DIM * 4);
    int*      src_s  = (int*)alloc((size_t)N_EDGES * 4);
    int*      deg    = (int*)alloc((size_t)N_NODES * 4);
    int*      offs   = (int*)alloc((size_t)N_NODES * 4);
    int*      cursor = (int*)alloc((size_t)N_NODES * 4);
    int*      bsum   = (int*)alloc(64 * 4);
    float*    Wc     = (float*)alloc((size_t)NLAYER * EDGE_DIM * HID * 4);
    float*    cc     = (float*)alloc((size_t)NLAYER * HID * 4);
    ushort_t* w0T    = (ushort_t*)alloc((size_t)HID * IN_CH * 2);
    ushort_t* w1T    = (ushort_t*)alloc((size_t)NLAYER * HID2 * HID * 2);
    ushort_t* w2T    = (ushort_t*)alloc((size_t)NLAYER * HID * HID2 * 2);
    float*    bnsum  = (float*)alloc(HID * 4);
    float*    bnssq  = (float*)alloc(HID * 4);
    float*    bnA    = (float*)alloc(HID * 4);
    float*    bnB    = (float*)alloc(HID * 4);
    int*      gstart = (int*)alloc((NGRAPH + 1) * 4);
    float*    pooled = (float*)alloc((size_t)NGRAPH * HID * 4);

    hipMemsetAsync(deg, 0, (size_t)N_NODES * 4, stream);
    hipMemsetAsync(cursor, 0, (size_t)N_NODES * 4, stream);

    k_transpose_cvt<<<64, 256, 0, stream>>>(node_w, w0T, 1, IN_CH, HID);
    k_transpose_cvt<<<640, 256, 0, stream>>>(m1w, w1T, NLAYER, HID, HID2);
    k_transpose_cvt<<<640, 256, 0, stream>>>(m2w, w2T, NLAYER, HID2, HID);
    k_combine<<<NLAYER, HID, 0, stream>>>(edge_w, edge_b, lin_w, lin_b, Wc, cc);

    k_hist<<<N_EDGES / 256, 256, 0, stream>>>(ei, deg);
    k_scan1<<<49, 1024, 0, stream>>>(deg, offs, bsum);
    k_scan2<<<1, 1, 0, stream>>>(bsum, 49);
    k_scan3<<<49, 1024, 0, stream>>>(offs, bsum);
    k_scatter<<<N_EDGES / 256, 256, 0, stream>>>(ei, ea, offs, cursor, src_s, ea_s);

    k_node_enc<<<NPAD / 64, 256, 0, stream>>>(x, w0T, node_b, h);

    for (int l = 0; l < NLAYER; ++l) {
        k_edge<<<N_NODES / 2, 256, 0, stream>>>(Wc, cc, ea_s, src_s, offs, deg, h, epsv, z, l);
        k_mlp1<<<NPAD / 64, 256, 0, stream>>>(z, w1T, m1b, ibuf, l);
        hipMemsetAsync(bnsum, 0, HID * 4, stream);
        hipMemsetAsync(bnssq, 0, HID * 4, stream);
        k_mlp2<<<NPAD / 64, 256, 0, stream>>>(ibuf, w2T, m2b, z2, bnsum, bnssq, l);
        k_bnfin<<<1, HID, 0, stream>>>(bnsum, bnssq, bng, bnb, bnA, bnB, l);
        k_resid<<<(N_NODES * HID) / 1024, 1024, 0, stream>>>(z2, bnA, bnB, h);
    }

    k_gstart<<<1, 256, 0, stream>>>(batch, gstart);
    k_pool<<<NGRAPH, HID, 0, stream>>>(h, gstart, pooled, (float*)d_out + NGRAPH * HID);
    k_outmlp<<<NGRAPH, HID, 0, stream>>>(pooled, ow1, ob1, ow2, ob2, (float*)d_out);
}